// Round 4
// baseline (318.320 us; speedup 1.0000x reference)
//
#include <hip/hip_runtime.h>

#define B_ 16
#define C_ 12
#define H_ 384
#define W_ 384
#define LK 96
#define HW_ (H_ * W_)            // 147456
#define CHW (C_ * HW_)           // 1769472
#define LK2 (LK * LK)            // 9216
#define TPB 256
#define NTH (B_ / 2 * H_ * (W_ / 4))   // 294912 threads, 2 streams each
#define NBLK (NTH / TPB)               // 1152 blocks — fully resident, no tail
#define NTOT ((double)(B_ * C_ * H_ * W_))

__device__ __forceinline__ float mask_w(float v) {
    // Sequential threshold masking collapses to 3 compares (verified absmax=0).
    const float T2 = (133.0f - 33.44f) / 47.54f;
    const float T3 = (181.0f - 33.44f) / 47.54f;
    const float T4 = (255.0f - 33.44f) / 47.54f;
    return v < T2 ? 5.0f : (v < T3 ? 10.0f : (v < T4 ? 30.0f : v));
}

// One channel-step of the fused loss for one 4-pixel stream.
__device__ __forceinline__ void step(
    const float4& vt, const float4& vp, const float4& xv, float fh,
    float c0, float c1, float c2, float d0, float d1, float d2,
    float4& s, float4& t, float& acc)
{
    const float e0 = c0 + fh * (d0 - c0);
    const float e1 = c1 + fh * (d1 - c1);
    const float e2 = c2 + fh * (d2 - c2);
    const float b0 = 0.375f * e0 + 0.625f * e1;
    const float b1 = 0.125f * e0 + 0.875f * e1;
    const float b2 = 0.875f * e1 + 0.125f * e2;
    const float b3 = 0.625f * e1 + 0.375f * e2;
    acc += (mask_w(vt.x) + s.x + t.x) * fabsf(vp.x - vt.x);
    s.x += fabsf(vt.x - xv.x); t.x += b0;
    acc += (mask_w(vt.y) + s.y + t.y) * fabsf(vp.y - vt.y);
    s.y += fabsf(vt.y - xv.y); t.y += b1;
    acc += (mask_w(vt.z) + s.z + t.z) * fabsf(vp.z - vt.z);
    s.z += fabsf(vt.z - xv.z); t.z += b2;
    acc += (mask_w(vt.w) + s.w + t.w) * fabsf(vp.w - vt.w);
    s.w += fabsf(vt.w - xv.w); t.w += b3;
}

__global__ __launch_bounds__(TPB, 5) void loss_main(
    const float* __restrict__ y_pre, const float* __restrict__ y_true,
    const float* __restrict__ x_l, const float* __restrict__ wlk,
    double* __restrict__ partial)
{
    const int g = blockIdx.x * TPB + threadIdx.x;
    const int j = g % (W_ / 4);
    const int t = g / (W_ / 4);
    const int h = t % H_;
    const int b = t / H_;                     // 0..7; stream B = batch b+8

    // bilinear geometry (shared by both streams)
    const float src_h = h * 0.25f - 0.375f;
    const float kf = floorf(src_h);
    const float fh = src_h - kf;
    const int k0 = max((int)kf, 0);
    const int k1 = min((int)kf + 1, LK - 1);
    const int jm1 = max(j - 1, 0), jp1 = min(j + 1, LK - 1);
    const int rm0 = k0 * LK + jm1, rc0 = k0 * LK + j, rp0 = k0 * LK + jp1;
    const int rm1 = k1 * LK + jm1, rc1 = k1 * LK + j, rp1 = k1 * LK + jp1;

    const int pix = h * W_ + j * 4;
    const float4 xA = *(const float4*)(x_l + b * HW_ + pix);
    const float4 xB = *(const float4*)(x_l + (b + 8) * HW_ + pix);

    const float* ytA = y_true + (size_t)b * CHW + pix;
    const float* ytB = ytA + (size_t)8 * CHW;
    const float* ypA = y_pre + (size_t)b * CHW + pix;
    const float* ypB = ypA + (size_t)8 * CHW;
    const float* LA = wlk + (size_t)b * C_ * LK2;
    const float* LB = LA + (size_t)8 * C_ * LK2;

    float4 sA = {0,0,0,0}, tA = {0,0,0,0};
    float4 sB = {0,0,0,0}, tB = {0,0,0,0};
    float accA = 0.f, accB = 0.f;

    // prologue: channel 0 in flight
    float4 vtA = *(const float4*)ytA, vpA = *(const float4*)ypA;
    float4 vtB = *(const float4*)ytB, vpB = *(const float4*)ypB;
    float cA0 = LA[rm0], cA1 = LA[rc0], cA2 = LA[rp0];
    float dA0 = LA[rm1], dA1 = LA[rc1], dA2 = LA[rp1];
    float cB0 = LB[rm0], cB1 = LB[rc0], cB2 = LB[rp0];
    float dB0 = LB[rm1], dB1 = LB[rc1], dB2 = LB[rp1];

    #pragma unroll
    for (int c = 0; c < C_; ++c) {
        float4 ntA, npA, ntB, npB;
        float nA0, nA1, nA2, mA0, mA1, mA2;
        float nB0, nB1, nB2, mB0, mB1, mB2;
        if (c + 1 < C_) {                      // prefetch next channel
            const int yo = (c + 1) * HW_;
            ntA = *(const float4*)(ytA + yo);  npA = *(const float4*)(ypA + yo);
            ntB = *(const float4*)(ytB + yo);  npB = *(const float4*)(ypB + yo);
            const int lo = (c + 1) * LK2;
            nA0 = LA[lo + rm0]; nA1 = LA[lo + rc0]; nA2 = LA[lo + rp0];
            mA0 = LA[lo + rm1]; mA1 = LA[lo + rc1]; mA2 = LA[lo + rp1];
            nB0 = LB[lo + rm0]; nB1 = LB[lo + rc0]; nB2 = LB[lo + rp0];
            mB0 = LB[lo + rm1]; mB1 = LB[lo + rc1]; mB2 = LB[lo + rp1];
        }
        step(vtA, vpA, xA, fh, cA0, cA1, cA2, dA0, dA1, dA2, sA, tA, accA);
        step(vtB, vpB, xB, fh, cB0, cB1, cB2, dB0, dB1, dB2, sB, tB, accB);
        if (c + 1 < C_) {                      // rotate buffers
            vtA = ntA; vpA = npA; vtB = ntB; vpB = npB;
            cA0 = nA0; cA1 = nA1; cA2 = nA2; dA0 = mA0; dA1 = mA1; dA2 = mA2;
            cB0 = nB0; cB1 = nB1; cB2 = nB2; dB0 = mB0; dB1 = mB1; dB2 = mB2;
        }
    }

    // --- block reduction (double) ---
    double v = (double)accA + (double)accB;
    #pragma unroll
    for (int off = 32; off > 0; off >>= 1) v += __shfl_down(v, off, 64);
    __shared__ double lds[TPB / 64];
    const int lane = threadIdx.x & 63, wid = threadIdx.x >> 6;
    if (lane == 0) lds[wid] = v;
    __syncthreads();
    if (threadIdx.x == 0)
        partial[blockIdx.x] = lds[0] + lds[1] + lds[2] + lds[3];
}

__global__ __launch_bounds__(256) void loss_final(
    const double* __restrict__ partial, float* __restrict__ out)
{
    double v = 0.0;
    for (int i = threadIdx.x; i < NBLK; i += 256) v += partial[i];
    #pragma unroll
    for (int off = 32; off > 0; off >>= 1) v += __shfl_down(v, off, 64);
    __shared__ double lds[4];
    const int lane = threadIdx.x & 63, wid = threadIdx.x >> 6;
    if (lane == 0) lds[wid] = v;
    __syncthreads();
    if (threadIdx.x == 0)
        out[0] = (float)((lds[0] + lds[1] + lds[2] + lds[3]) / NTOT);
}

extern "C" void kernel_launch(void* const* d_in, const int* in_sizes, int n_in,
                              void* d_out, int out_size, void* d_ws, size_t ws_size,
                              hipStream_t stream) {
    const float* y_pre  = (const float*)d_in[0];
    const float* y_true = (const float*)d_in[1];
    const float* x_l    = (const float*)d_in[2];
    const float* wlk    = (const float*)d_in[3];
    double* partial = (double*)d_ws;   // NBLK*8 = 9216 bytes

    loss_main<<<NBLK, TPB, 0, stream>>>(y_pre, y_true, x_l, wlk, partial);
    loss_final<<<1, 256, 0, stream>>>(partial, (float*)d_out);
}

// Round 5
// 106.568 us; speedup vs baseline: 2.9870x; 2.9870x over previous
//
#include <hip/hip_runtime.h>

#define B_ 16
#define C_ 12
#define H_ 384
#define W_ 384
#define LK 96
#define HW_ (H_ * W_)            // 147456
#define CHW (C_ * HW_)           // 1769472
#define LK2 (LK * LK)            // 9216
#define TPB 256
#define NTH (B_ / 2 * H_ * (W_ / 4))   // 294912 threads, 2 batch-streams each
#define NBLK (NTH / TPB)               // 1152 blocks
#define NTOT ((double)(B_ * C_ * H_ * W_))

__device__ __forceinline__ float mask_w(float v) {
    // Sequential threshold masking collapses to 3 compares (verified absmax=0).
    const float T2 = (133.0f - 33.44f) / 47.54f;
    const float T3 = (181.0f - 33.44f) / 47.54f;
    const float T4 = (255.0f - 33.44f) / 47.54f;
    return v < T2 ? 5.0f : (v < T3 ? 10.0f : (v < T4 ? 30.0f : v));
}

// One channel-step of the fused loss for one 4-pixel stream.
__device__ __forceinline__ void step(
    const float4& vt, const float4& vp, const float4& xv, float fh,
    float c0, float c1, float c2, float d0, float d1, float d2,
    float4& s, float4& t, float& acc)
{
    const float e0 = c0 + fh * (d0 - c0);
    const float e1 = c1 + fh * (d1 - c1);
    const float e2 = c2 + fh * (d2 - c2);
    acc += (mask_w(vt.x) + s.x + t.x) * fabsf(vp.x - vt.x);
    s.x += fabsf(vt.x - xv.x); t.x += 0.375f * e0 + 0.625f * e1;
    acc += (mask_w(vt.y) + s.y + t.y) * fabsf(vp.y - vt.y);
    s.y += fabsf(vt.y - xv.y); t.y += 0.125f * e0 + 0.875f * e1;
    acc += (mask_w(vt.z) + s.z + t.z) * fabsf(vp.z - vt.z);
    s.z += fabsf(vt.z - xv.z); t.z += 0.875f * e1 + 0.125f * e2;
    acc += (mask_w(vt.w) + s.w + t.w) * fabsf(vp.w - vt.w);
    s.w += fabsf(vt.w - xv.w); t.w += 0.625f * e1 + 0.375f * e2;
}

__global__ __launch_bounds__(TPB) void loss_main(
    const float* __restrict__ y_pre, const float* __restrict__ y_true,
    const float* __restrict__ x_l, const float* __restrict__ wlk,
    double* __restrict__ partial, unsigned* __restrict__ cnt,
    float* __restrict__ out)
{
    const int g = blockIdx.x * TPB + threadIdx.x;
    const int j = g % (W_ / 4);
    const int t = g / (W_ / 4);
    const int h = t % H_;
    const int b = t / H_;                     // 0..7; stream B = batch b+8

    // bilinear geometry (shared by both streams)
    const float src_h = h * 0.25f - 0.375f;
    const float kf = floorf(src_h);
    const float fh = src_h - kf;
    const int k0 = max((int)kf, 0);
    const int k1 = min((int)kf + 1, LK - 1);
    const int jm1 = max(j - 1, 0), jp1 = min(j + 1, LK - 1);
    const int rm0 = k0 * LK + jm1, rc0 = k0 * LK + j, rp0 = k0 * LK + jp1;
    const int rm1 = k1 * LK + jm1, rc1 = k1 * LK + j, rp1 = k1 * LK + jp1;

    const int pix = h * W_ + j * 4;
    const float4 xA = *(const float4*)(x_l + b * HW_ + pix);
    const float4 xB = *(const float4*)(x_l + (b + 8) * HW_ + pix);

    const float* ytA = y_true + (size_t)b * CHW + pix;
    const float* ypA = y_pre + (size_t)b * CHW + pix;
    const float* LA = wlk + (size_t)b * C_ * LK2;

    float4 sA = {0,0,0,0}, tA = {0,0,0,0};
    float4 sB = {0,0,0,0}, tB = {0,0,0,0};
    float accA = 0.f, accB = 0.f;

    #pragma unroll
    for (int c = 0; c < C_; ++c) {
        const int yo = c * HW_;
        const int lo = c * LK2;
        const float4 vtA = *(const float4*)(ytA + yo);
        const float4 vpA = *(const float4*)(ypA + yo);
        const float4 vtB = *(const float4*)(ytA + 8 * CHW + yo);
        const float4 vpB = *(const float4*)(ypA + 8 * CHW + yo);
        const float cA0 = LA[lo + rm0], cA1 = LA[lo + rc0], cA2 = LA[lo + rp0];
        const float dA0 = LA[lo + rm1], dA1 = LA[lo + rc1], dA2 = LA[lo + rp1];
        const float cB0 = LA[8 * C_ * LK2 + lo + rm0], cB1 = LA[8 * C_ * LK2 + lo + rc0],
                    cB2 = LA[8 * C_ * LK2 + lo + rp0];
        const float dB0 = LA[8 * C_ * LK2 + lo + rm1], dB1 = LA[8 * C_ * LK2 + lo + rc1],
                    dB2 = LA[8 * C_ * LK2 + lo + rp1];
        step(vtA, vpA, xA, fh, cA0, cA1, cA2, dA0, dA1, dA2, sA, tA, accA);
        step(vtB, vpB, xB, fh, cB0, cB1, cB2, dB0, dB1, dB2, sB, tB, accB);
    }

    // --- block reduction (double) ---
    double v = (double)accA + (double)accB;
    #pragma unroll
    for (int off = 32; off > 0; off >>= 1) v += __shfl_down(v, off, 64);
    __shared__ double lds[TPB / 64];
    __shared__ int is_last;
    const int lane = threadIdx.x & 63, wid = threadIdx.x >> 6;
    if (lane == 0) lds[wid] = v;
    __syncthreads();
    if (threadIdx.x == 0) {
        const double bsum = lds[0] + lds[1] + lds[2] + lds[3];
        __hip_atomic_store(&partial[blockIdx.x], bsum, __ATOMIC_RELAXED,
                           __HIP_MEMORY_SCOPE_AGENT);
        __threadfence();                                   // release
        const unsigned ticket =
            __hip_atomic_fetch_add(cnt, 1u, __ATOMIC_ACQ_REL, __HIP_MEMORY_SCOPE_AGENT);
        is_last = (ticket == NBLK - 1);
    }
    __syncthreads();
    if (!is_last) return;

    // --- last block finalizes (fixed order -> deterministic) ---
    __threadfence();                                       // acquire
    double f = 0.0;
    for (int i = threadIdx.x; i < NBLK; i += TPB)
        f += __hip_atomic_load(&partial[i], __ATOMIC_RELAXED, __HIP_MEMORY_SCOPE_AGENT);
    #pragma unroll
    for (int off = 32; off > 0; off >>= 1) f += __shfl_down(f, off, 64);
    __syncthreads();                                       // reuse lds safely
    if (lane == 0) lds[wid] = f;
    __syncthreads();
    if (threadIdx.x == 0)
        out[0] = (float)((lds[0] + lds[1] + lds[2] + lds[3]) / NTOT);
}

extern "C" void kernel_launch(void* const* d_in, const int* in_sizes, int n_in,
                              void* d_out, int out_size, void* d_ws, size_t ws_size,
                              hipStream_t stream) {
    const float* y_pre  = (const float*)d_in[0];
    const float* y_true = (const float*)d_in[1];
    const float* x_l    = (const float*)d_in[2];
    const float* wlk    = (const float*)d_in[3];
    double* partial = (double*)d_ws;                       // NBLK*8 bytes
    unsigned* cnt   = (unsigned*)((char*)d_ws + NBLK * 8); // +4 bytes

    hipMemsetAsync(cnt, 0, sizeof(unsigned), stream);      // graph-capture legal
    loss_main<<<NBLK, TPB, 0, stream>>>(y_pre, y_true, x_l, wlk,
                                        partial, cnt, (float*)d_out);
}